// Round 1
// baseline (907.825 us; speedup 1.0000x reference)
//
#include <hip/hip_runtime.h>
#include <hip/hip_bf16.h>
#include <stdint.h>

#define N_NODES 100000
#define N_EDGES 3200000
#define F_IN    512
#define HIDDEN  64
#define NCLS    64

typedef float v4f __attribute__((ext_vector_type(4)));
typedef short v8s __attribute__((ext_vector_type(8)));

// fp32 -> bf16 bits, round-to-nearest-even
__device__ __forceinline__ unsigned short f2bf(float f){
  unsigned u = __float_as_uint(f);
  u += 0x7fffu + ((u >> 16) & 1u);
  return (unsigned short)(u >> 16);
}

// ---------------------------------------------------------------------------
// Pre-pack W1/W2 into MFMA B-fragment order: [kstep][ntile][lane][j] bf16.
// B[k = q*8+j][n = nt*16 + (lane&15)], q = lane>>4. Same (q,j)->k formula as
// the A-operand fill, so any HW k-permutation cancels.
// ---------------------------------------------------------------------------
__global__ void prep_weights(const float* __restrict__ W1, const float* __restrict__ W2,
                             unsigned short* __restrict__ w1f, unsigned short* __restrict__ w2f){
  int t = blockIdx.x * 256 + threadIdx.x;
  if (t < 16*4*64*8){
    int j = t & 7, lane = (t >> 3) & 63, nt = (t >> 9) & 3, ks = t >> 11;
    int m = lane & 15, q = lane >> 4;
    int k = ks*32 + q*8 + j, n = nt*16 + m;
    w1f[t] = f2bf(W1[k*HIDDEN + n]);
  } else {
    int u = t - 16*4*64*8;
    if (u < 2*4*64*8){
      int j = u & 7, lane = (u >> 3) & 63, nt = (u >> 9) & 3, ks = u >> 11;
      int m = lane & 15, q = lane >> 4;
      int k = ks*32 + q*8 + j, n = nt*16 + m;
      w2f[u] = f2bf(W2[k*NCLS + n]);
    }
  }
}

// ---------------------------------------------------------------------------
// Fused MLP: logits(bf16) = relu(X@W1+b1)@W2+b2. One wave = 16 nodes.
// GEMM1: A direct from global (converted to bf16), B from prepacked w1f.
// h -> LDS (fp32, stride 68 to keep 2-way-max bank aliasing) -> A-frags for
// GEMM2. C/D layout: col=lane&15, row=quad*4+reg (measured, m89/m91).
// ---------------------------------------------------------------------------
__global__ __launch_bounds__(256) void mlp_kernel(
    const float* __restrict__ X, const float* __restrict__ b1,
    const float* __restrict__ b2,
    const unsigned short* __restrict__ w1f, const unsigned short* __restrict__ w2f,
    unsigned short* __restrict__ logits){
  __shared__ __align__(16) float lds[4][16][68];
  int tid  = threadIdx.x;
  int wid  = tid >> 6, lane = tid & 63;
  int m    = lane & 15, q = lane >> 4;
  int base = blockIdx.x * 64 + wid * 16;
  if (base > N_NODES - 16) base = N_NODES - 16;   // tail waves redo last tile (benign)

  const float* rp = X + (size_t)(base + m) * F_IN + q * 8;
  const v8s* w1v = (const v8s*)w1f;
  const v8s* w2v = (const v8s*)w2f;

  v4f a0c = {0,0,0,0}, a1c = {0,0,0,0}, a2c = {0,0,0,0}, a3c = {0,0,0,0};
  #pragma unroll
  for (int ks = 0; ks < 16; ++ks){
    const float4* pa = (const float4*)(rp + ks * 32);
    float4 x0 = pa[0], x1 = pa[1];
    v8s af;
    af[0]=(short)f2bf(x0.x); af[1]=(short)f2bf(x0.y); af[2]=(short)f2bf(x0.z); af[3]=(short)f2bf(x0.w);
    af[4]=(short)f2bf(x1.x); af[5]=(short)f2bf(x1.y); af[6]=(short)f2bf(x1.z); af[7]=(short)f2bf(x1.w);
    a0c = __builtin_amdgcn_mfma_f32_16x16x32_bf16(af, w1v[(ks*4+0)*64 + lane], a0c, 0,0,0);
    a1c = __builtin_amdgcn_mfma_f32_16x16x32_bf16(af, w1v[(ks*4+1)*64 + lane], a1c, 0,0,0);
    a2c = __builtin_amdgcn_mfma_f32_16x16x32_bf16(af, w1v[(ks*4+2)*64 + lane], a2c, 0,0,0);
    a3c = __builtin_amdgcn_mfma_f32_16x16x32_bf16(af, w1v[(ks*4+3)*64 + lane], a3c, 0,0,0);
  }

  float b1v0 = b1[m], b1v1 = b1[16+m], b1v2 = b1[32+m], b1v3 = b1[48+m];
  #pragma unroll
  for (int r = 0; r < 4; ++r){
    int row = q*4 + r;
    lds[wid][row][     m] = fmaxf(a0c[r] + b1v0, 0.f);
    lds[wid][row][16 + m] = fmaxf(a1c[r] + b1v1, 0.f);
    lds[wid][row][32 + m] = fmaxf(a2c[r] + b1v2, 0.f);
    lds[wid][row][48 + m] = fmaxf(a3c[r] + b1v3, 0.f);
  }
  __syncthreads();

  v4f c0 = {0,0,0,0}, c1 = {0,0,0,0}, c2 = {0,0,0,0}, c3 = {0,0,0,0};
  #pragma unroll
  for (int k2 = 0; k2 < 2; ++k2){
    const float4* ph = (const float4*)&lds[wid][m][k2*32 + q*8];
    float4 h0 = ph[0], h1 = ph[1];
    v8s af;
    af[0]=(short)f2bf(h0.x); af[1]=(short)f2bf(h0.y); af[2]=(short)f2bf(h0.z); af[3]=(short)f2bf(h0.w);
    af[4]=(short)f2bf(h1.x); af[5]=(short)f2bf(h1.y); af[6]=(short)f2bf(h1.z); af[7]=(short)f2bf(h1.w);
    c0 = __builtin_amdgcn_mfma_f32_16x16x32_bf16(af, w2v[(k2*4+0)*64 + lane], c0, 0,0,0);
    c1 = __builtin_amdgcn_mfma_f32_16x16x32_bf16(af, w2v[(k2*4+1)*64 + lane], c1, 0,0,0);
    c2 = __builtin_amdgcn_mfma_f32_16x16x32_bf16(af, w2v[(k2*4+2)*64 + lane], c2, 0,0,0);
    c3 = __builtin_amdgcn_mfma_f32_16x16x32_bf16(af, w2v[(k2*4+3)*64 + lane], c3, 0,0,0);
  }

  float b2v0 = b2[m], b2v1 = b2[16+m], b2v2 = b2[32+m], b2v3 = b2[48+m];
  unsigned short* lp = logits + (size_t)base * NCLS;
  #pragma unroll
  for (int r = 0; r < 4; ++r){
    int row = q*4 + r;
    lp[row*NCLS +      m] = f2bf(c0[r] + b2v0);
    lp[row*NCLS + 16 + m] = f2bf(c1[r] + b2v1);
    lp[row*NCLS + 32 + m] = f2bf(c2[r] + b2v2);
    lp[row*NCLS + 48 + m] = f2bf(c3[r] + b2v3);
  }
}

// ---------------------------------------------------------------------------
// CSR build: histogram -> two-level exclusive scan -> placement (counting sort)
// ---------------------------------------------------------------------------
__global__ void hist_kernel(const int* __restrict__ rows, int* __restrict__ cnt){
  int e = blockIdx.x * 256 + threadIdx.x;
  if (e < N_EDGES) atomicAdd(&cnt[rows[e]], 1);
}

__global__ void scan_part(const int* __restrict__ cnt, int* __restrict__ bsum){
  int b = blockIdx.x, t = threadIdx.x;
  int base = b * 1024 + t * 4;
  int s = 0;
  #pragma unroll
  for (int k = 0; k < 4; ++k){ int i = base + k; if (i < N_NODES) s += cnt[i]; }
  for (int o = 32; o > 0; o >>= 1) s += __shfl_down(s, o);
  __shared__ int wsum[4];
  if ((t & 63) == 0) wsum[t >> 6] = s;
  __syncthreads();
  if (t == 0) bsum[b] = wsum[0] + wsum[1] + wsum[2] + wsum[3];
}

__global__ void scan_top(const int* __restrict__ bsum, int* __restrict__ boff){
  __shared__ int sh[128];
  int t = threadIdx.x;
  int v = (t < 98) ? bsum[t] : 0;
  sh[t] = v; __syncthreads();
  for (int o = 1; o < 128; o <<= 1){
    int add = (t >= o) ? sh[t - o] : 0;
    __syncthreads();
    sh[t] += add;
    __syncthreads();
  }
  if (t < 98) boff[t] = sh[t] - v;   // exclusive
}

__global__ void scan_final(const int* __restrict__ cnt, const int* __restrict__ boff,
                           int* __restrict__ offs, int* __restrict__ cursor){
  __shared__ int sh[256];
  int b = blockIdx.x, t = threadIdx.x;
  int base = b * 1024 + t * 4;
  int v0 = (base+0 < N_NODES) ? cnt[base+0] : 0;
  int v1 = (base+1 < N_NODES) ? cnt[base+1] : 0;
  int v2 = (base+2 < N_NODES) ? cnt[base+2] : 0;
  int v3 = (base+3 < N_NODES) ? cnt[base+3] : 0;
  int s = v0 + v1 + v2 + v3;
  sh[t] = s; __syncthreads();
  for (int o = 1; o < 256; o <<= 1){
    int add = (t >= o) ? sh[t - o] : 0;
    __syncthreads();
    sh[t] += add;
    __syncthreads();
  }
  int run = boff[b] + sh[t] - s;
  if (base+0 < N_NODES){ offs[base+0] = run; cursor[base+0] = run; run += v0; }
  if (base+1 < N_NODES){ offs[base+1] = run; cursor[base+1] = run; run += v1; }
  if (base+2 < N_NODES){ offs[base+2] = run; cursor[base+2] = run; run += v2; }
  if (base+3 < N_NODES){ offs[base+3] = run; cursor[base+3] = run; run += v3; }
  if (b == 0 && t == 0) offs[N_NODES] = N_EDGES;
}

__global__ void place_kernel(const int* __restrict__ rows, const int* __restrict__ cols,
                             const float* __restrict__ vals, int* __restrict__ cursor,
                             int* __restrict__ sc, float* __restrict__ sv){
  int e = blockIdx.x * 256 + threadIdx.x;
  if (e < N_EDGES){
    int p = atomicAdd(&cursor[rows[e]], 1);
    sc[p] = cols[e];
    sv[p] = vals[e];
  }
}

// One wave per node: lane c accumulates channel c over the node's edge list.
__global__ __launch_bounds__(256) void agg_kernel(
    const int* __restrict__ offs, const int* __restrict__ sc,
    const float* __restrict__ sv, const unsigned short* __restrict__ logits,
    float* __restrict__ out){
  int n = blockIdx.x * 4 + (threadIdx.x >> 6);
  int c = threadIdx.x & 63;
  int s = offs[n], e = offs[n + 1];
  float acc = 0.f;
  for (int i = s; i < e; ++i){
    float lv = __uint_as_float(((unsigned)logits[(size_t)sc[i] * NCLS + c]) << 16);
    acc = fmaf(sv[i], lv, acc);
  }
  out[(size_t)n * NCLS + c] = acc;
}

// Fallback if workspace is too small for the sort arrays: direct atomic scatter.
__global__ void scatter_atomic(const int* __restrict__ rows, const int* __restrict__ cols,
                               const float* __restrict__ vals,
                               const unsigned short* __restrict__ logits,
                               float* __restrict__ out){
  long g = (long)blockIdx.x * 256 + threadIdx.x;
  int e = (int)(g >> 6), c = (int)(g & 63);
  if (e < N_EDGES){
    float lv = __uint_as_float(((unsigned)logits[(size_t)cols[e] * NCLS + c]) << 16);
    atomicAdd(&out[(size_t)rows[e] * NCLS + c], vals[e] * lv);
  }
}

extern "C" void kernel_launch(void* const* d_in, const int* in_sizes, int n_in,
                              void* d_out, int out_size, void* d_ws, size_t ws_size,
                              hipStream_t stream){
  const float* X     = (const float*)d_in[0];
  const int*   erows = (const int*)  d_in[1];
  const int*   ecols = (const int*)  d_in[2];
  const float* evals = (const float*)d_in[3];
  const float* W1    = (const float*)d_in[4];
  const float* b1    = (const float*)d_in[5];
  const float* W2    = (const float*)d_in[6];
  const float* b2    = (const float*)d_in[7];
  float* out = (float*)d_out;

  char* ws = (char*)d_ws;
  size_t off = 0;
  auto alloc = [&](size_t bytes) -> char* {
    char* p = ws + off;
    off = (off + bytes + 255) & ~(size_t)255;
    return p;
  };
  unsigned short* logits = (unsigned short*)alloc((size_t)N_NODES * NCLS * 2); // 12.8 MB
  unsigned short* w1f    = (unsigned short*)alloc(16*4*64*8 * 2);
  unsigned short* w2f    = (unsigned short*)alloc(2*4*64*8 * 2);
  int* cnt    = (int*)alloc((size_t)N_NODES * 4);
  int* offs   = (int*)alloc((size_t)(N_NODES + 1) * 4);
  int* cursor = (int*)alloc((size_t)N_NODES * 4);
  int* bsum   = (int*)alloc(128 * 4);
  int* boff   = (int*)alloc(128 * 4);
  int*   sc = (int*)  alloc((size_t)N_EDGES * 4);
  float* sv = (float*)alloc((size_t)N_EDGES * 4);
  size_t full_need = off;   // ~39.7 MB

  prep_weights<<<144, 256, 0, stream>>>(W1, W2, w1f, w2f);
  mlp_kernel<<<(N_NODES + 63) / 64, 256, 0, stream>>>(X, b1, b2, w1f, w2f, logits);

  if (ws_size >= full_need){
    hipMemsetAsync(cnt, 0, (size_t)N_NODES * 4, stream);
    hist_kernel <<<(N_EDGES + 255) / 256, 256, 0, stream>>>(erows, cnt);
    scan_part   <<<98, 256, 0, stream>>>(cnt, bsum);
    scan_top    <<<1, 128, 0, stream>>>(bsum, boff);
    scan_final  <<<98, 256, 0, stream>>>(cnt, boff, offs, cursor);
    place_kernel<<<(N_EDGES + 255) / 256, 256, 0, stream>>>(erows, ecols, evals, cursor, sc, sv);
    agg_kernel  <<<N_NODES / 4, 256, 0, stream>>>(offs, sc, sv, logits, out);
  } else {
    hipMemsetAsync(out, 0, (size_t)N_NODES * NCLS * 4, stream);
    scatter_atomic<<<(int)(((long)N_EDGES * 64 + 255) / 256), 256, 0, stream>>>(
        erows, ecols, evals, logits, out);
  }
}

// Round 2
// 793.490 us; speedup vs baseline: 1.1441x; 1.1441x over previous
//
#include <hip/hip_runtime.h>
#include <hip/hip_bf16.h>
#include <stdint.h>

#define N_NODES 100000
#define N_EDGES 3200000
#define F_IN    512
#define HIDDEN  64
#define NCLS    64

typedef float v4f __attribute__((ext_vector_type(4)));
typedef short v8s __attribute__((ext_vector_type(8)));

// fp32 -> bf16 bits, round-to-nearest-even
__device__ __forceinline__ unsigned short f2bf(float f){
  unsigned u = __float_as_uint(f);
  u += 0x7fffu + ((u >> 16) & 1u);
  return (unsigned short)(u >> 16);
}

// ---------------------------------------------------------------------------
// Pre-pack W1/W2 into MFMA B-fragment order: [kstep][ntile][lane][j] bf16.
// ---------------------------------------------------------------------------
__global__ void prep_weights(const float* __restrict__ W1, const float* __restrict__ W2,
                             unsigned short* __restrict__ w1f, unsigned short* __restrict__ w2f){
  int t = blockIdx.x * 256 + threadIdx.x;
  if (t < 16*4*64*8){
    int j = t & 7, lane = (t >> 3) & 63, nt = (t >> 9) & 3, ks = t >> 11;
    int m = lane & 15, q = lane >> 4;
    int k = ks*32 + q*8 + j, n = nt*16 + m;
    w1f[t] = f2bf(W1[k*HIDDEN + n]);
  } else {
    int u = t - 16*4*64*8;
    if (u < 2*4*64*8){
      int j = u & 7, lane = (u >> 3) & 63, nt = (u >> 9) & 3, ks = u >> 11;
      int m = lane & 15, q = lane >> 4;
      int k = ks*32 + q*8 + j, n = nt*16 + m;
      w2f[u] = f2bf(W2[k*NCLS + n]);
    }
  }
}

// ---------------------------------------------------------------------------
// Fused MLP: logits(bf16) = relu(X@W1+b1)@W2+b2. One wave = 16 nodes.
// C/D layout: col=lane&15, row=quad*4+reg (measured, m89/m91).
// ---------------------------------------------------------------------------
__global__ __launch_bounds__(256) void mlp_kernel(
    const float* __restrict__ X, const float* __restrict__ b1,
    const float* __restrict__ b2,
    const unsigned short* __restrict__ w1f, const unsigned short* __restrict__ w2f,
    unsigned short* __restrict__ logits){
  __shared__ __align__(16) float lds[4][16][68];
  int tid  = threadIdx.x;
  int wid  = tid >> 6, lane = tid & 63;
  int m    = lane & 15, q = lane >> 4;
  int base = blockIdx.x * 64 + wid * 16;
  if (base > N_NODES - 16) base = N_NODES - 16;   // tail waves redo last tile (benign)

  const float* rp = X + (size_t)(base + m) * F_IN + q * 8;
  const v8s* w1v = (const v8s*)w1f;
  const v8s* w2v = (const v8s*)w2f;

  v4f a0c = {0,0,0,0}, a1c = {0,0,0,0}, a2c = {0,0,0,0}, a3c = {0,0,0,0};
  #pragma unroll
  for (int ks = 0; ks < 16; ++ks){
    const float4* pa = (const float4*)(rp + ks * 32);
    float4 x0 = pa[0], x1 = pa[1];
    v8s af;
    af[0]=(short)f2bf(x0.x); af[1]=(short)f2bf(x0.y); af[2]=(short)f2bf(x0.z); af[3]=(short)f2bf(x0.w);
    af[4]=(short)f2bf(x1.x); af[5]=(short)f2bf(x1.y); af[6]=(short)f2bf(x1.z); af[7]=(short)f2bf(x1.w);
    a0c = __builtin_amdgcn_mfma_f32_16x16x32_bf16(af, w1v[(ks*4+0)*64 + lane], a0c, 0,0,0);
    a1c = __builtin_amdgcn_mfma_f32_16x16x32_bf16(af, w1v[(ks*4+1)*64 + lane], a1c, 0,0,0);
    a2c = __builtin_amdgcn_mfma_f32_16x16x32_bf16(af, w1v[(ks*4+2)*64 + lane], a2c, 0,0,0);
    a3c = __builtin_amdgcn_mfma_f32_16x16x32_bf16(af, w1v[(ks*4+3)*64 + lane], a3c, 0,0,0);
  }

  float b1v0 = b1[m], b1v1 = b1[16+m], b1v2 = b1[32+m], b1v3 = b1[48+m];
  #pragma unroll
  for (int r = 0; r < 4; ++r){
    int row = q*4 + r;
    lds[wid][row][     m] = fmaxf(a0c[r] + b1v0, 0.f);
    lds[wid][row][16 + m] = fmaxf(a1c[r] + b1v1, 0.f);
    lds[wid][row][32 + m] = fmaxf(a2c[r] + b1v2, 0.f);
    lds[wid][row][48 + m] = fmaxf(a3c[r] + b1v3, 0.f);
  }
  __syncthreads();

  v4f c0 = {0,0,0,0}, c1 = {0,0,0,0}, c2 = {0,0,0,0}, c3 = {0,0,0,0};
  #pragma unroll
  for (int k2 = 0; k2 < 2; ++k2){
    const float4* ph = (const float4*)&lds[wid][m][k2*32 + q*8];
    float4 h0 = ph[0], h1 = ph[1];
    v8s af;
    af[0]=(short)f2bf(h0.x); af[1]=(short)f2bf(h0.y); af[2]=(short)f2bf(h0.z); af[3]=(short)f2bf(h0.w);
    af[4]=(short)f2bf(h1.x); af[5]=(short)f2bf(h1.y); af[6]=(short)f2bf(h1.z); af[7]=(short)f2bf(h1.w);
    c0 = __builtin_amdgcn_mfma_f32_16x16x32_bf16(af, w2v[(k2*4+0)*64 + lane], c0, 0,0,0);
    c1 = __builtin_amdgcn_mfma_f32_16x16x32_bf16(af, w2v[(k2*4+1)*64 + lane], c1, 0,0,0);
    c2 = __builtin_amdgcn_mfma_f32_16x16x32_bf16(af, w2v[(k2*4+2)*64 + lane], c2, 0,0,0);
    c3 = __builtin_amdgcn_mfma_f32_16x16x32_bf16(af, w2v[(k2*4+3)*64 + lane], c3, 0,0,0);
  }

  float b2v0 = b2[m], b2v1 = b2[16+m], b2v2 = b2[32+m], b2v3 = b2[48+m];
  unsigned short* lp = logits + (size_t)base * NCLS;
  #pragma unroll
  for (int r = 0; r < 4; ++r){
    int row = q*4 + r;
    lp[row*NCLS +      m] = f2bf(c0[r] + b2v0);
    lp[row*NCLS + 16 + m] = f2bf(c1[r] + b2v1);
    lp[row*NCLS + 32 + m] = f2bf(c2[r] + b2v2);
    lp[row*NCLS + 48 + m] = f2bf(c3[r] + b2v3);
  }
}

// ---------------------------------------------------------------------------
// CSR build: histogram -> two-level exclusive scan -> placement (counting sort)
// ---------------------------------------------------------------------------
__global__ void hist_kernel(const int* __restrict__ rows, int* __restrict__ cnt){
  int e4 = (blockIdx.x * 256 + threadIdx.x) * 4;
  int4 r = *(const int4*)(rows + e4);          // N_EDGES % 4 == 0
  atomicAdd(&cnt[r.x], 1);
  atomicAdd(&cnt[r.y], 1);
  atomicAdd(&cnt[r.z], 1);
  atomicAdd(&cnt[r.w], 1);
}

__global__ void scan_part(const int* __restrict__ cnt, int* __restrict__ bsum){
  int b = blockIdx.x, t = threadIdx.x;
  int base = b * 1024 + t * 4;
  int s = 0;
  #pragma unroll
  for (int k = 0; k < 4; ++k){ int i = base + k; if (i < N_NODES) s += cnt[i]; }
  for (int o = 32; o > 0; o >>= 1) s += __shfl_down(s, o);
  __shared__ int wsum[4];
  if ((t & 63) == 0) wsum[t >> 6] = s;
  __syncthreads();
  if (t == 0) bsum[b] = wsum[0] + wsum[1] + wsum[2] + wsum[3];
}

__global__ void scan_top(const int* __restrict__ bsum, int* __restrict__ boff){
  __shared__ int sh[128];
  int t = threadIdx.x;
  int v = (t < 98) ? bsum[t] : 0;
  sh[t] = v; __syncthreads();
  for (int o = 1; o < 128; o <<= 1){
    int add = (t >= o) ? sh[t - o] : 0;
    __syncthreads();
    sh[t] += add;
    __syncthreads();
  }
  if (t < 98) boff[t] = sh[t] - v;   // exclusive
}

__global__ void scan_final(const int* __restrict__ cnt, const int* __restrict__ boff,
                           int* __restrict__ offs, int* __restrict__ cursor){
  __shared__ int sh[256];
  int b = blockIdx.x, t = threadIdx.x;
  int base = b * 1024 + t * 4;
  int v0 = (base+0 < N_NODES) ? cnt[base+0] : 0;
  int v1 = (base+1 < N_NODES) ? cnt[base+1] : 0;
  int v2 = (base+2 < N_NODES) ? cnt[base+2] : 0;
  int v3 = (base+3 < N_NODES) ? cnt[base+3] : 0;
  int s = v0 + v1 + v2 + v3;
  sh[t] = s; __syncthreads();
  for (int o = 1; o < 256; o <<= 1){
    int add = (t >= o) ? sh[t - o] : 0;
    __syncthreads();
    sh[t] += add;
    __syncthreads();
  }
  int run = boff[b] + sh[t] - s;
  if (base+0 < N_NODES){ offs[base+0] = run; cursor[base+0] = run; run += v0; }
  if (base+1 < N_NODES){ offs[base+1] = run; cursor[base+1] = run; run += v1; }
  if (base+2 < N_NODES){ offs[base+2] = run; cursor[base+2] = run; run += v2; }
  if (base+3 < N_NODES){ offs[base+3] = run; cursor[base+3] = run; run += v3; }
  if (b == 0 && t == 0) offs[N_NODES] = N_EDGES;
}

// Placement: one 8B (col,val) scatter per edge instead of two 4B scatters.
__global__ void place_kernel(const int* __restrict__ rows, const int* __restrict__ cols,
                             const float* __restrict__ vals, int* __restrict__ cursor,
                             int2* __restrict__ edges){
  int e4 = (blockIdx.x * 256 + threadIdx.x) * 4;
  int4   r = *(const int4*)  (rows + e4);
  int4   c = *(const int4*)  (cols + e4);
  float4 v = *(const float4*)(vals + e4);
  int p0 = atomicAdd(&cursor[r.x], 1);
  int p1 = atomicAdd(&cursor[r.y], 1);
  int p2 = atomicAdd(&cursor[r.z], 1);
  int p3 = atomicAdd(&cursor[r.w], 1);
  edges[p0] = make_int2(c.x, __float_as_int(v.x));
  edges[p1] = make_int2(c.y, __float_as_int(v.y));
  edges[p2] = make_int2(c.z, __float_as_int(v.z));
  edges[p3] = make_int2(c.w, __float_as_int(v.w));
}

// ---------------------------------------------------------------------------
// Aggregate: one wave per node. Lanes 0-31 handle even pair-edge, 32-63 odd.
// Each lane loads uint = 2 bf16 channels -> 256 B/gather covering 2 edges.
// Unroll 4 pairs = 8 edges/iter -> 4 independent gathers in flight.
// ---------------------------------------------------------------------------
__global__ __launch_bounds__(256) void agg_kernel(
    const int* __restrict__ offs, const int2* __restrict__ edges,
    const unsigned short* __restrict__ logits, float* __restrict__ out){
  int n   = blockIdx.x * 4 + (threadIdx.x >> 6);
  int lane = threadIdx.x & 63;
  int h   = lane & 31;      // uint index within a logits row (2 channels)
  int sel = lane >> 5;      // which edge of the pair this half-wave handles
  int s = offs[n], e = offs[n + 1];
  const unsigned* lg = (const unsigned*)logits;   // 32 uints per node row

  float acc0 = 0.f, acc1 = 0.f;   // channels 2h, 2h+1
  int i = s;
  for (; i + 8 <= e; i += 8){
    int2 e0 = edges[i     + sel];
    int2 e1 = edges[i + 2 + sel];
    int2 e2 = edges[i + 4 + sel];
    int2 e3 = edges[i + 6 + sel];
    unsigned u0 = lg[((size_t)e0.x << 5) + h];
    unsigned u1 = lg[((size_t)e1.x << 5) + h];
    unsigned u2 = lg[((size_t)e2.x << 5) + h];
    unsigned u3 = lg[((size_t)e3.x << 5) + h];
    float v0 = __int_as_float(e0.y), v1 = __int_as_float(e1.y);
    float v2 = __int_as_float(e2.y), v3 = __int_as_float(e3.y);
    acc0 = fmaf(v0, __uint_as_float(u0 << 16),         acc0);
    acc1 = fmaf(v0, __uint_as_float(u0 & 0xffff0000u), acc1);
    acc0 = fmaf(v1, __uint_as_float(u1 << 16),         acc0);
    acc1 = fmaf(v1, __uint_as_float(u1 & 0xffff0000u), acc1);
    acc0 = fmaf(v2, __uint_as_float(u2 << 16),         acc0);
    acc1 = fmaf(v2, __uint_as_float(u2 & 0xffff0000u), acc1);
    acc0 = fmaf(v3, __uint_as_float(u3 << 16),         acc0);
    acc1 = fmaf(v3, __uint_as_float(u3 & 0xffff0000u), acc1);
  }
  for (; i < e; i += 2){
    int idx = i + sel;
    int col = 0; float v = 0.f;
    if (idx < e){ int2 ev = edges[idx]; col = ev.x; v = __int_as_float(ev.y); }
    unsigned u = lg[((size_t)col << 5) + h];
    acc0 = fmaf(v, __uint_as_float(u << 16),         acc0);
    acc1 = fmaf(v, __uint_as_float(u & 0xffff0000u), acc1);
  }
  // combine the two half-wave partial sums (same channels, disjoint edges)
  acc0 += __shfl_xor(acc0, 32);
  acc1 += __shfl_xor(acc1, 32);
  if (sel == 0){
    float2* op = (float2*)(out + (size_t)n * NCLS);
    op[h] = make_float2(acc0, acc1);
  }
}

// Fallback if workspace is too small for the sort arrays: direct atomic scatter.
__global__ void scatter_atomic(const int* __restrict__ rows, const int* __restrict__ cols,
                               const float* __restrict__ vals,
                               const unsigned short* __restrict__ logits,
                               float* __restrict__ out){
  long g = (long)blockIdx.x * 256 + threadIdx.x;
  int e = (int)(g >> 6), c = (int)(g & 63);
  if (e < N_EDGES){
    float lv = __uint_as_float(((unsigned)logits[(size_t)cols[e] * NCLS + c]) << 16);
    atomicAdd(&out[(size_t)rows[e] * NCLS + c], vals[e] * lv);
  }
}

extern "C" void kernel_launch(void* const* d_in, const int* in_sizes, int n_in,
                              void* d_out, int out_size, void* d_ws, size_t ws_size,
                              hipStream_t stream){
  const float* X     = (const float*)d_in[0];
  const int*   erows = (const int*)  d_in[1];
  const int*   ecols = (const int*)  d_in[2];
  const float* evals = (const float*)d_in[3];
  const float* W1    = (const float*)d_in[4];
  const float* b1    = (const float*)d_in[5];
  const float* W2    = (const float*)d_in[6];
  const float* b2    = (const float*)d_in[7];
  float* out = (float*)d_out;

  char* ws = (char*)d_ws;
  size_t off = 0;
  auto alloc = [&](size_t bytes) -> char* {
    char* p = ws + off;
    off = (off + bytes + 255) & ~(size_t)255;
    return p;
  };
  unsigned short* logits = (unsigned short*)alloc((size_t)N_NODES * NCLS * 2); // 12.8 MB
  unsigned short* w1f    = (unsigned short*)alloc(16*4*64*8 * 2);
  unsigned short* w2f    = (unsigned short*)alloc(2*4*64*8 * 2);
  int* cnt    = (int*)alloc((size_t)N_NODES * 4);
  int* offs   = (int*)alloc((size_t)(N_NODES + 1) * 4);
  int* cursor = (int*)alloc((size_t)N_NODES * 4);
  int* bsum   = (int*)alloc(128 * 4);
  int* boff   = (int*)alloc(128 * 4);
  int2* edges = (int2*)alloc((size_t)N_EDGES * 8);   // packed (col, val)
  size_t full_need = off;   // ~39.7 MB

  prep_weights<<<144, 256, 0, stream>>>(W1, W2, w1f, w2f);
  mlp_kernel<<<(N_NODES + 63) / 64, 256, 0, stream>>>(X, b1, b2, w1f, w2f, logits);

  if (ws_size >= full_need){
    hipMemsetAsync(cnt, 0, (size_t)N_NODES * 4, stream);
    hist_kernel <<<N_EDGES / 4 / 256, 256, 0, stream>>>(erows, cnt);
    scan_part   <<<98, 256, 0, stream>>>(cnt, bsum);
    scan_top    <<<1, 128, 0, stream>>>(bsum, boff);
    scan_final  <<<98, 256, 0, stream>>>(cnt, boff, offs, cursor);
    place_kernel<<<N_EDGES / 4 / 256, 256, 0, stream>>>(erows, ecols, evals, cursor, edges);
    agg_kernel  <<<N_NODES / 4, 256, 0, stream>>>(offs, edges, logits, out);
  } else {
    hipMemsetAsync(out, 0, (size_t)N_NODES * NCLS * 4, stream);
    scatter_atomic<<<(int)(((long)N_EDGES * 64 + 255) / 256), 256, 0, stream>>>(
        erows, ecols, evals, logits, out);
  }
}

// Round 3
// 659.580 us; speedup vs baseline: 1.3764x; 1.2030x over previous
//
#include <hip/hip_runtime.h>
#include <hip/hip_bf16.h>
#include <stdint.h>

#define N_NODES 100000
#define N_EDGES 3200000
#define F_IN    512
#define HIDDEN  64
#define NCLS    64

#define BROWS   128                 // rows per bucket
#define NBKT    782                 // ceil(N_NODES / BROWS)
#define NBKT_PAD 1024
#define CHUNK   4096                // edges per bucket_scatter block

typedef float v4f __attribute__((ext_vector_type(4)));
typedef short v8s __attribute__((ext_vector_type(8)));

// fp32 -> bf16 bits, round-to-nearest-even
__device__ __forceinline__ unsigned short f2bf(float f){
  unsigned u = __float_as_uint(f);
  u += 0x7fffu + ((u >> 16) & 1u);
  return (unsigned short)(u >> 16);
}

// ---------------------------------------------------------------------------
// Pre-pack W1/W2 into MFMA B-fragment order: [kstep][ntile][lane][j] bf16.
// ---------------------------------------------------------------------------
__global__ void prep_weights(const float* __restrict__ W1, const float* __restrict__ W2,
                             unsigned short* __restrict__ w1f, unsigned short* __restrict__ w2f){
  int t = blockIdx.x * 256 + threadIdx.x;
  if (t < 16*4*64*8){
    int j = t & 7, lane = (t >> 3) & 63, nt = (t >> 9) & 3, ks = t >> 11;
    int m = lane & 15, q = lane >> 4;
    int k = ks*32 + q*8 + j, n = nt*16 + m;
    w1f[t] = f2bf(W1[k*HIDDEN + n]);
  } else {
    int u = t - 16*4*64*8;
    if (u < 2*4*64*8){
      int j = u & 7, lane = (u >> 3) & 63, nt = (u >> 9) & 3, ks = u >> 11;
      int m = lane & 15, q = lane >> 4;
      int k = ks*32 + q*8 + j, n = nt*16 + m;
      w2f[u] = f2bf(W2[k*NCLS + n]);
    }
  }
}

// ---------------------------------------------------------------------------
// Fused MLP: logits(bf16) = relu(X@W1+b1)@W2+b2. One wave = 16 nodes.
// C/D layout: col=lane&15, row=quad*4+reg (measured, m89/m91).
// ---------------------------------------------------------------------------
__global__ __launch_bounds__(256) void mlp_kernel(
    const float* __restrict__ X, const float* __restrict__ b1,
    const float* __restrict__ b2,
    const unsigned short* __restrict__ w1f, const unsigned short* __restrict__ w2f,
    unsigned short* __restrict__ logits){
  __shared__ __align__(16) float lds[4][16][68];
  int tid  = threadIdx.x;
  int wid  = tid >> 6, lane = tid & 63;
  int m    = lane & 15, q = lane >> 4;
  int base = blockIdx.x * 64 + wid * 16;
  if (base > N_NODES - 16) base = N_NODES - 16;   // tail waves redo last tile (benign)

  const float* rp = X + (size_t)(base + m) * F_IN + q * 8;
  const v8s* w1v = (const v8s*)w1f;
  const v8s* w2v = (const v8s*)w2f;

  v4f a0c = {0,0,0,0}, a1c = {0,0,0,0}, a2c = {0,0,0,0}, a3c = {0,0,0,0};
  #pragma unroll
  for (int ks = 0; ks < 16; ++ks){
    const float4* pa = (const float4*)(rp + ks * 32);
    float4 x0 = pa[0], x1 = pa[1];
    v8s af;
    af[0]=(short)f2bf(x0.x); af[1]=(short)f2bf(x0.y); af[2]=(short)f2bf(x0.z); af[3]=(short)f2bf(x0.w);
    af[4]=(short)f2bf(x1.x); af[5]=(short)f2bf(x1.y); af[6]=(short)f2bf(x1.z); af[7]=(short)f2bf(x1.w);
    a0c = __builtin_amdgcn_mfma_f32_16x16x32_bf16(af, w1v[(ks*4+0)*64 + lane], a0c, 0,0,0);
    a1c = __builtin_amdgcn_mfma_f32_16x16x32_bf16(af, w1v[(ks*4+1)*64 + lane], a1c, 0,0,0);
    a2c = __builtin_amdgcn_mfma_f32_16x16x32_bf16(af, w1v[(ks*4+2)*64 + lane], a2c, 0,0,0);
    a3c = __builtin_amdgcn_mfma_f32_16x16x32_bf16(af, w1v[(ks*4+3)*64 + lane], a3c, 0,0,0);
  }

  float b1v0 = b1[m], b1v1 = b1[16+m], b1v2 = b1[32+m], b1v3 = b1[48+m];
  #pragma unroll
  for (int r = 0; r < 4; ++r){
    int row = q*4 + r;
    lds[wid][row][     m] = fmaxf(a0c[r] + b1v0, 0.f);
    lds[wid][row][16 + m] = fmaxf(a1c[r] + b1v1, 0.f);
    lds[wid][row][32 + m] = fmaxf(a2c[r] + b1v2, 0.f);
    lds[wid][row][48 + m] = fmaxf(a3c[r] + b1v3, 0.f);
  }
  __syncthreads();

  v4f c0 = {0,0,0,0}, c1 = {0,0,0,0}, c2 = {0,0,0,0}, c3 = {0,0,0,0};
  #pragma unroll
  for (int k2 = 0; k2 < 2; ++k2){
    const float4* ph = (const float4*)&lds[wid][m][k2*32 + q*8];
    float4 h0 = ph[0], h1 = ph[1];
    v8s af;
    af[0]=(short)f2bf(h0.x); af[1]=(short)f2bf(h0.y); af[2]=(short)f2bf(h0.z); af[3]=(short)f2bf(h0.w);
    af[4]=(short)f2bf(h1.x); af[5]=(short)f2bf(h1.y); af[6]=(short)f2bf(h1.z); af[7]=(short)f2bf(h1.w);
    c0 = __builtin_amdgcn_mfma_f32_16x16x32_bf16(af, w2v[(k2*4+0)*64 + lane], c0, 0,0,0);
    c1 = __builtin_amdgcn_mfma_f32_16x16x32_bf16(af, w2v[(k2*4+1)*64 + lane], c1, 0,0,0);
    c2 = __builtin_amdgcn_mfma_f32_16x16x32_bf16(af, w2v[(k2*4+2)*64 + lane], c2, 0,0,0);
    c3 = __builtin_amdgcn_mfma_f32_16x16x32_bf16(af, w2v[(k2*4+3)*64 + lane], c3, 0,0,0);
  }

  float b2v0 = b2[m], b2v1 = b2[16+m], b2v2 = b2[32+m], b2v3 = b2[48+m];
  unsigned short* lp = logits + (size_t)base * NCLS;
  #pragma unroll
  for (int r = 0; r < 4; ++r){
    int row = q*4 + r;
    lp[row*NCLS +      m] = f2bf(c0[r] + b2v0);
    lp[row*NCLS + 16 + m] = f2bf(c1[r] + b2v1);
    lp[row*NCLS + 32 + m] = f2bf(c2[r] + b2v2);
    lp[row*NCLS + 48 + m] = f2bf(c3[r] + b2v3);
  }
}

// ---------------------------------------------------------------------------
// CSR build: histogram -> two-level exclusive scan -> two-pass binned sort
// ---------------------------------------------------------------------------
__global__ void hist_kernel(const int* __restrict__ rows, int* __restrict__ cnt){
  int e4 = (blockIdx.x * 256 + threadIdx.x) * 4;
  int4 r = *(const int4*)(rows + e4);          // N_EDGES % 4 == 0
  atomicAdd(&cnt[r.x], 1);
  atomicAdd(&cnt[r.y], 1);
  atomicAdd(&cnt[r.z], 1);
  atomicAdd(&cnt[r.w], 1);
}

__global__ void scan_part(const int* __restrict__ cnt, int* __restrict__ bsum){
  int b = blockIdx.x, t = threadIdx.x;
  int base = b * 1024 + t * 4;
  int s = 0;
  #pragma unroll
  for (int k = 0; k < 4; ++k){ int i = base + k; if (i < N_NODES) s += cnt[i]; }
  for (int o = 32; o > 0; o >>= 1) s += __shfl_down(s, o);
  __shared__ int wsum[4];
  if ((t & 63) == 0) wsum[t >> 6] = s;
  __syncthreads();
  if (t == 0) bsum[b] = wsum[0] + wsum[1] + wsum[2] + wsum[3];
}

__global__ void scan_top(const int* __restrict__ bsum, int* __restrict__ boff){
  __shared__ int sh[128];
  int t = threadIdx.x;
  int v = (t < 98) ? bsum[t] : 0;
  sh[t] = v; __syncthreads();
  for (int o = 1; o < 128; o <<= 1){
    int add = (t >= o) ? sh[t - o] : 0;
    __syncthreads();
    sh[t] += add;
    __syncthreads();
  }
  if (t < 98) boff[t] = sh[t] - v;   // exclusive
}

__global__ void scan_final(const int* __restrict__ cnt, const int* __restrict__ boff,
                           int* __restrict__ offs){
  __shared__ int sh[256];
  int b = blockIdx.x, t = threadIdx.x;
  int base = b * 1024 + t * 4;
  int v0 = (base+0 < N_NODES) ? cnt[base+0] : 0;
  int v1 = (base+1 < N_NODES) ? cnt[base+1] : 0;
  int v2 = (base+2 < N_NODES) ? cnt[base+2] : 0;
  int v3 = (base+3 < N_NODES) ? cnt[base+3] : 0;
  int s = v0 + v1 + v2 + v3;
  sh[t] = s; __syncthreads();
  for (int o = 1; o < 256; o <<= 1){
    int add = (t >= o) ? sh[t - o] : 0;
    __syncthreads();
    sh[t] += add;
    __syncthreads();
  }
  int run = boff[b] + sh[t] - s;
  if (base+0 < N_NODES){ offs[base+0] = run; run += v0; }
  if (base+1 < N_NODES){ offs[base+1] = run; run += v1; }
  if (base+2 < N_NODES){ offs[base+2] = run; run += v2; }
  if (base+3 < N_NODES){ offs[base+3] = run; run += v3; }
  if (b == 0 && t == 0) offs[N_NODES] = N_EDGES;
}

// bucket cursors = CSR offset at each bucket's first row
__global__ void binit(const int* __restrict__ offs, int* __restrict__ bcur){
  int b = blockIdx.x * 256 + threadIdx.x;
  if (b < NBKT) bcur[b] = offs[b * BROWS];
}

// ---------------------------------------------------------------------------
// Pass 1: scatter edges into 128-row buckets. LDS staging makes the global
// writes quasi-coalesced (contiguous run per bucket per block) instead of
// 3.2M isolated 8B lines (which cost 8x writeback amplification in R2).
// Payload packs local_row(7b)<<17 | col(17b) so pass 2 needn't re-read rows.
// ---------------------------------------------------------------------------
__global__ __launch_bounds__(256) void bucket_scatter(
    const int* __restrict__ rows, const int* __restrict__ cols,
    const float* __restrict__ vals, int* __restrict__ bcur,
    int2* __restrict__ ebkt){
  __shared__ int  lcnt[NBKT_PAD];   // counts -> exclusive prefix -> cursor
  __shared__ int  lbase[NBKT_PAD];  // global dest base minus local prefix
  __shared__ int  ssum[256];
  __shared__ int2 stage[CHUNK];     // 32 KB
  __shared__ int  sdst[CHUNK];      // 16 KB: dest-base per staged slot
  int t = threadIdx.x;
  int base = blockIdx.x * CHUNK;
  int cnt  = min(CHUNK, N_EDGES - base);

  #pragma unroll
  for (int i = 0; i < 4; ++i) lcnt[t*4 + i] = 0;
  __syncthreads();

  int r[16];
  #pragma unroll
  for (int k = 0; k < 16; ++k){
    int li = t + k*256;
    if (li < cnt){
      r[k] = rows[base + li];
      atomicAdd(&lcnt[r[k] >> 7], 1);
    } else r[k] = -1;
  }
  __syncthreads();

  // block-exclusive scan over 1024 counters (4 per thread)
  int v0 = lcnt[t*4], v1 = lcnt[t*4+1], v2 = lcnt[t*4+2], v3 = lcnt[t*4+3];
  int s = v0 + v1 + v2 + v3;
  ssum[t] = s; __syncthreads();
  for (int o = 1; o < 256; o <<= 1){
    int add = (t >= o) ? ssum[t - o] : 0;
    __syncthreads();
    ssum[t] += add;
    __syncthreads();
  }
  int run = ssum[t] - s;
  int e0 = run, e1 = run + v0, e2 = run + v0 + v1, e3 = run + v0 + v1 + v2;
  if (v0){ int g = atomicAdd(&bcur[t*4+0], v0); lbase[t*4+0] = g - e0; }
  if (v1){ int g = atomicAdd(&bcur[t*4+1], v1); lbase[t*4+1] = g - e1; }
  if (v2){ int g = atomicAdd(&bcur[t*4+2], v2); lbase[t*4+2] = g - e2; }
  if (v3){ int g = atomicAdd(&bcur[t*4+3], v3); lbase[t*4+3] = g - e3; }
  lcnt[t*4+0] = e0; lcnt[t*4+1] = e1; lcnt[t*4+2] = e2; lcnt[t*4+3] = e3;
  __syncthreads();

  // rank into LDS stage, bucket-sorted
  #pragma unroll
  for (int k = 0; k < 16; ++k){
    if (r[k] >= 0){
      int li = t + k*256;
      int c  = cols[base + li];
      float v = vals[base + li];
      int b  = r[k] >> 7;
      int pos = atomicAdd(&lcnt[b], 1);
      stage[pos] = make_int2(((r[k] & 127) << 17) | c, __float_as_int(v));
      sdst[pos]  = lbase[b];
    }
  }
  __syncthreads();

  // writeout: consecutive j within a bucket -> consecutive global addresses
  for (int j = t; j < cnt; j += 256){
    ebkt[sdst[j] + j] = stage[j];
  }
}

// ---------------------------------------------------------------------------
// Pass 2: one block per bucket; finish sort with 128 LDS row-cursors. Writes
// are scattered only within this bucket's ~33 KB CSR segment (L2-resident,
// fully written by this block -> no writeback amplification).
// ---------------------------------------------------------------------------
__global__ __launch_bounds__(256) void bucket_sort(
    const int* __restrict__ offs, const int2* __restrict__ ebkt,
    int2* __restrict__ edges){
  __shared__ int cur[BROWS];
  int b = blockIdx.x, t = threadIdx.x;
  int row0 = b * BROWS;
  if (t < BROWS){
    int rr = row0 + t;
    cur[t] = (rr < N_NODES) ? offs[rr] : N_EDGES;
  }
  __syncthreads();
  int s = offs[row0];
  int e = offs[min(row0 + BROWS, N_NODES)];
  for (int i = s + t; i < e; i += 256){
    int2 ev = ebkt[i];
    int lr  = ((unsigned)ev.x) >> 17;
    int pos = atomicAdd(&cur[lr], 1);
    edges[pos] = make_int2(ev.x & 0x1FFFF, ev.y);
  }
}

// ---------------------------------------------------------------------------
// Aggregate: one wave per node, half-wave per edge of a pair, uint = 2 bf16
// channels per lane, 4 independent 256B gathers in flight.
// ---------------------------------------------------------------------------
__global__ __launch_bounds__(256) void agg_kernel(
    const int* __restrict__ offs, const int2* __restrict__ edges,
    const unsigned short* __restrict__ logits, float* __restrict__ out){
  int n   = blockIdx.x * 4 + (threadIdx.x >> 6);
  int lane = threadIdx.x & 63;
  int h   = lane & 31;
  int sel = lane >> 5;
  int s = offs[n], e = offs[n + 1];
  const unsigned* lg = (const unsigned*)logits;

  float acc0 = 0.f, acc1 = 0.f;
  int i = s;
  for (; i + 8 <= e; i += 8){
    int2 e0 = edges[i     + sel];
    int2 e1 = edges[i + 2 + sel];
    int2 e2 = edges[i + 4 + sel];
    int2 e3 = edges[i + 6 + sel];
    unsigned u0 = lg[((size_t)e0.x << 5) + h];
    unsigned u1 = lg[((size_t)e1.x << 5) + h];
    unsigned u2 = lg[((size_t)e2.x << 5) + h];
    unsigned u3 = lg[((size_t)e3.x << 5) + h];
    float v0 = __int_as_float(e0.y), v1 = __int_as_float(e1.y);
    float v2 = __int_as_float(e2.y), v3 = __int_as_float(e3.y);
    acc0 = fmaf(v0, __uint_as_float(u0 << 16),         acc0);
    acc1 = fmaf(v0, __uint_as_float(u0 & 0xffff0000u), acc1);
    acc0 = fmaf(v1, __uint_as_float(u1 << 16),         acc0);
    acc1 = fmaf(v1, __uint_as_float(u1 & 0xffff0000u), acc1);
    acc0 = fmaf(v2, __uint_as_float(u2 << 16),         acc0);
    acc1 = fmaf(v2, __uint_as_float(u2 & 0xffff0000u), acc1);
    acc0 = fmaf(v3, __uint_as_float(u3 << 16),         acc0);
    acc1 = fmaf(v3, __uint_as_float(u3 & 0xffff0000u), acc1);
  }
  for (; i < e; i += 2){
    int idx = i + sel;
    int col = 0; float v = 0.f;
    if (idx < e){ int2 ev = edges[idx]; col = ev.x; v = __int_as_float(ev.y); }
    unsigned u = lg[((size_t)col << 5) + h];
    acc0 = fmaf(v, __uint_as_float(u << 16),         acc0);
    acc1 = fmaf(v, __uint_as_float(u & 0xffff0000u), acc1);
  }
  acc0 += __shfl_xor(acc0, 32);
  acc1 += __shfl_xor(acc1, 32);
  if (sel == 0){
    float2* op = (float2*)(out + (size_t)n * NCLS);
    op[h] = make_float2(acc0, acc1);
  }
}

// Fallback if workspace is too small: direct atomic scatter.
__global__ void scatter_atomic(const int* __restrict__ rows, const int* __restrict__ cols,
                               const float* __restrict__ vals,
                               const unsigned short* __restrict__ logits,
                               float* __restrict__ out){
  long g = (long)blockIdx.x * 256 + threadIdx.x;
  int e = (int)(g >> 6), c = (int)(g & 63);
  if (e < N_EDGES){
    float lv = __uint_as_float(((unsigned)logits[(size_t)cols[e] * NCLS + c]) << 16);
    atomicAdd(&out[(size_t)rows[e] * NCLS + c], vals[e] * lv);
  }
}

extern "C" void kernel_launch(void* const* d_in, const int* in_sizes, int n_in,
                              void* d_out, int out_size, void* d_ws, size_t ws_size,
                              hipStream_t stream){
  const float* X     = (const float*)d_in[0];
  const int*   erows = (const int*)  d_in[1];
  const int*   ecols = (const int*)  d_in[2];
  const float* evals = (const float*)d_in[3];
  const float* W1    = (const float*)d_in[4];
  const float* b1    = (const float*)d_in[5];
  const float* W2    = (const float*)d_in[6];
  const float* b2    = (const float*)d_in[7];
  float* out = (float*)d_out;

  char* ws = (char*)d_ws;
  size_t off = 0;
  auto alloc = [&](size_t bytes) -> char* {
    char* p = ws + off;
    off = (off + bytes + 255) & ~(size_t)255;
    return p;
  };
  unsigned short* logits = (unsigned short*)alloc((size_t)N_NODES * NCLS * 2); // 12.8 MB
  unsigned short* w1f    = (unsigned short*)alloc(16*4*64*8 * 2);
  unsigned short* w2f    = (unsigned short*)alloc(2*4*64*8 * 2);
  int* cnt  = (int*)alloc((size_t)N_NODES * 4);
  int* offs = (int*)alloc((size_t)(N_NODES + 1) * 4);
  int* bsum = (int*)alloc(128 * 4);
  int* boff = (int*)alloc(128 * 4);
  int* bcur = (int*)alloc((size_t)NBKT * 4);
  int2* ebkt  = (int2*)alloc((size_t)N_EDGES * 8);   // bucketed intermediate
  int2* edges = (int2*)alloc((size_t)N_EDGES * 8);   // final CSR (col, val)
  size_t full_need = off;   // ~65 MB

  prep_weights<<<144, 256, 0, stream>>>(W1, W2, w1f, w2f);
  mlp_kernel<<<(N_NODES + 63) / 64, 256, 0, stream>>>(X, b1, b2, w1f, w2f, logits);

  if (ws_size >= full_need){
    hipMemsetAsync(cnt, 0, (size_t)N_NODES * 4, stream);
    hist_kernel   <<<N_EDGES / 4 / 256, 256, 0, stream>>>(erows, cnt);
    scan_part     <<<98, 256, 0, stream>>>(cnt, bsum);
    scan_top      <<<1, 128, 0, stream>>>(bsum, boff);
    scan_final    <<<98, 256, 0, stream>>>(cnt, boff, offs);
    binit         <<<(NBKT + 255) / 256, 256, 0, stream>>>(offs, bcur);
    bucket_scatter<<<(N_EDGES + CHUNK - 1) / CHUNK, 256, 0, stream>>>(erows, ecols, evals, bcur, ebkt);
    bucket_sort   <<<NBKT, 256, 0, stream>>>(offs, ebkt, edges);
    agg_kernel    <<<N_NODES / 4, 256, 0, stream>>>(offs, edges, logits, out);
  } else {
    hipMemsetAsync(out, 0, (size_t)N_NODES * NCLS * 4, stream);
    scatter_atomic<<<(int)(((long)N_EDGES * 64 + 255) / 256), 256, 0, stream>>>(
        erows, ecols, evals, logits, out);
  }
}

// Round 4
// 518.634 us; speedup vs baseline: 1.7504x; 1.2718x over previous
//
#include <hip/hip_runtime.h>
#include <hip/hip_bf16.h>
#include <stdint.h>

#define N_NODES 100000
#define N_EDGES 3200000
#define F_IN    512
#define HIDDEN  64
#define NCLS    64

#define BROWS   128                 // rows per bucket
#define NBKT    782                 // ceil(N_NODES / BROWS)
#define NBKT_PAD 1024
#define CHUNK   4096                // edges per bucket_scatter block
#define EPB     16384               // edges per bucket_count block
#define NCB     ((N_EDGES + EPB - 1) / EPB)   // 196

typedef float v4f __attribute__((ext_vector_type(4)));
typedef short v8s __attribute__((ext_vector_type(8)));

// fp32 -> bf16 bits, round-to-nearest-even
__device__ __forceinline__ unsigned short f2bf(float f){
  unsigned u = __float_as_uint(f);
  u += 0x7fffu + ((u >> 16) & 1u);
  return (unsigned short)(u >> 16);
}
__device__ __forceinline__ float bflo(unsigned u){ return __uint_as_float(u << 16); }
__device__ __forceinline__ float bfhi(unsigned u){ return __uint_as_float(u & 0xffff0000u); }

// ---------------------------------------------------------------------------
// Pre-pack W1/W2 into MFMA B-fragment order: [kstep][ntile][lane][j] bf16.
// ---------------------------------------------------------------------------
__global__ void prep_weights(const float* __restrict__ W1, const float* __restrict__ W2,
                             unsigned short* __restrict__ w1f, unsigned short* __restrict__ w2f){
  int t = blockIdx.x * 256 + threadIdx.x;
  if (t < 16*4*64*8){
    int j = t & 7, lane = (t >> 3) & 63, nt = (t >> 9) & 3, ks = t >> 11;
    int m = lane & 15, q = lane >> 4;
    int k = ks*32 + q*8 + j, n = nt*16 + m;
    w1f[t] = f2bf(W1[k*HIDDEN + n]);
  } else {
    int u = t - 16*4*64*8;
    if (u < 2*4*64*8){
      int j = u & 7, lane = (u >> 3) & 63, nt = (u >> 9) & 3, ks = u >> 11;
      int m = lane & 15, q = lane >> 4;
      int k = ks*32 + q*8 + j, n = nt*16 + m;
      w2f[u] = f2bf(W2[k*NCLS + n]);
    }
  }
}

// ---------------------------------------------------------------------------
// Fused MLP: logits(bf16) = relu(X@W1+b1)@W2+b2. One wave = 16 nodes.
// C/D layout: col=lane&15, row=quad*4+reg (measured, m89/m91).
// ---------------------------------------------------------------------------
__global__ __launch_bounds__(256) void mlp_kernel(
    const float* __restrict__ X, const float* __restrict__ b1,
    const float* __restrict__ b2,
    const unsigned short* __restrict__ w1f, const unsigned short* __restrict__ w2f,
    unsigned short* __restrict__ logits){
  __shared__ __align__(16) float lds[4][16][68];
  int tid  = threadIdx.x;
  int wid  = tid >> 6, lane = tid & 63;
  int m    = lane & 15, q = lane >> 4;
  int base = blockIdx.x * 64 + wid * 16;
  if (base > N_NODES - 16) base = N_NODES - 16;   // tail waves redo last tile (benign)

  const float* rp = X + (size_t)(base + m) * F_IN + q * 8;
  const v8s* w1v = (const v8s*)w1f;
  const v8s* w2v = (const v8s*)w2f;

  v4f a0c = {0,0,0,0}, a1c = {0,0,0,0}, a2c = {0,0,0,0}, a3c = {0,0,0,0};
  #pragma unroll
  for (int ks = 0; ks < 16; ++ks){
    const float4* pa = (const float4*)(rp + ks * 32);
    float4 x0 = pa[0], x1 = pa[1];
    v8s af;
    af[0]=(short)f2bf(x0.x); af[1]=(short)f2bf(x0.y); af[2]=(short)f2bf(x0.z); af[3]=(short)f2bf(x0.w);
    af[4]=(short)f2bf(x1.x); af[5]=(short)f2bf(x1.y); af[6]=(short)f2bf(x1.z); af[7]=(short)f2bf(x1.w);
    a0c = __builtin_amdgcn_mfma_f32_16x16x32_bf16(af, w1v[(ks*4+0)*64 + lane], a0c, 0,0,0);
    a1c = __builtin_amdgcn_mfma_f32_16x16x32_bf16(af, w1v[(ks*4+1)*64 + lane], a1c, 0,0,0);
    a2c = __builtin_amdgcn_mfma_f32_16x16x32_bf16(af, w1v[(ks*4+2)*64 + lane], a2c, 0,0,0);
    a3c = __builtin_amdgcn_mfma_f32_16x16x32_bf16(af, w1v[(ks*4+3)*64 + lane], a3c, 0,0,0);
  }

  float b1v0 = b1[m], b1v1 = b1[16+m], b1v2 = b1[32+m], b1v3 = b1[48+m];
  #pragma unroll
  for (int r = 0; r < 4; ++r){
    int row = q*4 + r;
    lds[wid][row][     m] = fmaxf(a0c[r] + b1v0, 0.f);
    lds[wid][row][16 + m] = fmaxf(a1c[r] + b1v1, 0.f);
    lds[wid][row][32 + m] = fmaxf(a2c[r] + b1v2, 0.f);
    lds[wid][row][48 + m] = fmaxf(a3c[r] + b1v3, 0.f);
  }
  __syncthreads();

  v4f c0 = {0,0,0,0}, c1 = {0,0,0,0}, c2 = {0,0,0,0}, c3 = {0,0,0,0};
  #pragma unroll
  for (int k2 = 0; k2 < 2; ++k2){
    const float4* ph = (const float4*)&lds[wid][m][k2*32 + q*8];
    float4 h0 = ph[0], h1 = ph[1];
    v8s af;
    af[0]=(short)f2bf(h0.x); af[1]=(short)f2bf(h0.y); af[2]=(short)f2bf(h0.z); af[3]=(short)f2bf(h0.w);
    af[4]=(short)f2bf(h1.x); af[5]=(short)f2bf(h1.y); af[6]=(short)f2bf(h1.z); af[7]=(short)f2bf(h1.w);
    c0 = __builtin_amdgcn_mfma_f32_16x16x32_bf16(af, w2v[(k2*4+0)*64 + lane], c0, 0,0,0);
    c1 = __builtin_amdgcn_mfma_f32_16x16x32_bf16(af, w2v[(k2*4+1)*64 + lane], c1, 0,0,0);
    c2 = __builtin_amdgcn_mfma_f32_16x16x32_bf16(af, w2v[(k2*4+2)*64 + lane], c2, 0,0,0);
    c3 = __builtin_amdgcn_mfma_f32_16x16x32_bf16(af, w2v[(k2*4+3)*64 + lane], c3, 0,0,0);
  }

  float b2v0 = b2[m], b2v1 = b2[16+m], b2v2 = b2[32+m], b2v3 = b2[48+m];
  unsigned short* lp = logits + (size_t)base * NCLS;
  #pragma unroll
  for (int r = 0; r < 4; ++r){
    int row = q*4 + r;
    lp[row*NCLS +      m] = f2bf(c0[r] + b2v0);
    lp[row*NCLS + 16 + m] = f2bf(c1[r] + b2v1);
    lp[row*NCLS + 32 + m] = f2bf(c2[r] + b2v2);
    lp[row*NCLS + 48 + m] = f2bf(c3[r] + b2v3);
  }
}

// ---------------------------------------------------------------------------
// Per-bucket totals: LDS histogram per block, then <=782 global atomics/block.
// Replaces the 100k-counter global histogram (R3: 131 us, 99.8 MB writeback
// from cross-XCD atomic line ping-pong).
// ---------------------------------------------------------------------------
__global__ __launch_bounds__(256) void bucket_count(
    const int* __restrict__ rows, int* __restrict__ bcnt){
  __shared__ int lc[NBKT_PAD];
  int t = threadIdx.x;
  #pragma unroll
  for (int i = 0; i < 4; ++i) lc[t*4 + i] = 0;
  __syncthreads();
  int base = blockIdx.x * EPB;
  int cnt  = min(EPB, N_EDGES - base);     // always a multiple of 4
  const int4* rp = (const int4*)(rows + base);
  int nv = cnt >> 2;
  for (int i = t; i < nv; i += 256){
    int4 r = rp[i];
    atomicAdd(&lc[r.x >> 7], 1);
    atomicAdd(&lc[r.y >> 7], 1);
    atomicAdd(&lc[r.z >> 7], 1);
    atomicAdd(&lc[r.w >> 7], 1);
  }
  __syncthreads();
  for (int i = t; i < NBKT; i += 256){
    int v = lc[i];
    if (v) atomicAdd(&bcnt[i], v);
  }
}

// Single-block exclusive scan over 782 bucket counts -> bases + cursors.
__global__ __launch_bounds__(256) void bucket_scan(
    const int* __restrict__ bcnt, int* __restrict__ bbase, int* __restrict__ bcur,
    int* __restrict__ offs){
  __shared__ int ssum[256];
  int t = threadIdx.x;
  int v[4]; int s = 0;
  #pragma unroll
  for (int k = 0; k < 4; ++k){
    int i = t*4 + k;
    v[k] = (i < NBKT) ? bcnt[i] : 0;
    s += v[k];
  }
  ssum[t] = s; __syncthreads();
  for (int o = 1; o < 256; o <<= 1){
    int add = (t >= o) ? ssum[t - o] : 0;
    __syncthreads();
    ssum[t] += add;
    __syncthreads();
  }
  int run = ssum[t] - s;
  #pragma unroll
  for (int k = 0; k < 4; ++k){
    int i = t*4 + k;
    if (i < NBKT){ bbase[i] = run; bcur[i] = run; run += v[k]; }
  }
  if (t == 0){ bbase[NBKT] = N_EDGES; offs[N_NODES] = N_EDGES; }
}

// ---------------------------------------------------------------------------
// Pass 1: scatter edges into 128-row buckets via LDS staging (quasi-coalesced
// writes). Payload packs local_row(7b)<<17 | col(17b).
// ---------------------------------------------------------------------------
__global__ __launch_bounds__(256) void bucket_scatter(
    const int* __restrict__ rows, const int* __restrict__ cols,
    const float* __restrict__ vals, int* __restrict__ bcur,
    int2* __restrict__ ebkt){
  __shared__ int  lcnt[NBKT_PAD];   // counts -> exclusive prefix -> cursor
  __shared__ int  lbase[NBKT_PAD];  // global dest base minus local prefix
  __shared__ int  ssum[256];
  __shared__ int2 stage[CHUNK];     // 32 KB
  __shared__ int  sdst[CHUNK];      // 16 KB
  int t = threadIdx.x;
  int base = blockIdx.x * CHUNK;
  int cnt  = min(CHUNK, N_EDGES - base);

  #pragma unroll
  for (int i = 0; i < 4; ++i) lcnt[t*4 + i] = 0;
  __syncthreads();

  int r[16];
  #pragma unroll
  for (int k = 0; k < 16; ++k){
    int li = t + k*256;
    if (li < cnt){
      r[k] = rows[base + li];
      atomicAdd(&lcnt[r[k] >> 7], 1);
    } else r[k] = -1;
  }
  __syncthreads();

  int v0 = lcnt[t*4], v1 = lcnt[t*4+1], v2 = lcnt[t*4+2], v3 = lcnt[t*4+3];
  int s = v0 + v1 + v2 + v3;
  ssum[t] = s; __syncthreads();
  for (int o = 1; o < 256; o <<= 1){
    int add = (t >= o) ? ssum[t - o] : 0;
    __syncthreads();
    ssum[t] += add;
    __syncthreads();
  }
  int run = ssum[t] - s;
  int e0 = run, e1 = run + v0, e2 = run + v0 + v1, e3 = run + v0 + v1 + v2;
  if (v0){ int g = atomicAdd(&bcur[t*4+0], v0); lbase[t*4+0] = g - e0; }
  if (v1){ int g = atomicAdd(&bcur[t*4+1], v1); lbase[t*4+1] = g - e1; }
  if (v2){ int g = atomicAdd(&bcur[t*4+2], v2); lbase[t*4+2] = g - e2; }
  if (v3){ int g = atomicAdd(&bcur[t*4+3], v3); lbase[t*4+3] = g - e3; }
  lcnt[t*4+0] = e0; lcnt[t*4+1] = e1; lcnt[t*4+2] = e2; lcnt[t*4+3] = e3;
  __syncthreads();

  #pragma unroll
  for (int k = 0; k < 16; ++k){
    if (r[k] >= 0){
      int li = t + k*256;
      int c  = cols[base + li];
      float v = vals[base + li];
      int b  = r[k] >> 7;
      int pos = atomicAdd(&lcnt[b], 1);
      stage[pos] = make_int2(((r[k] & 127) << 17) | c, __float_as_int(v));
      sdst[pos]  = lbase[b];
    }
  }
  __syncthreads();

  for (int j = t; j < cnt; j += 256){
    ebkt[sdst[j] + j] = stage[j];
  }
}

// ---------------------------------------------------------------------------
// Pass 2: one block per bucket. Counts its 128 rows (LDS), scans them to get
// per-row CSR offsets (written to offs for agg), then finishes the sort.
// Scattered writes stay inside this bucket's ~33 KB L2-resident segment.
// ---------------------------------------------------------------------------
__global__ __launch_bounds__(256) void bucket_sort(
    const int* __restrict__ bbase, const int2* __restrict__ ebkt,
    int2* __restrict__ edges, int* __restrict__ offs){
  __shared__ int rc[BROWS];
  __shared__ int sc[BROWS];
  __shared__ int cur[BROWS];
  int b = blockIdx.x, t = threadIdx.x;
  int row0 = b * BROWS;
  int s = bbase[b], e = bbase[b + 1];
  if (t < BROWS) rc[t] = 0;
  __syncthreads();
  for (int i = s + t; i < e; i += 256){
    int lr = ((unsigned)ebkt[i].x) >> 17;
    atomicAdd(&rc[lr], 1);
  }
  __syncthreads();
  if (t < BROWS) sc[t] = rc[t];
  __syncthreads();
  for (int o = 1; o < BROWS; o <<= 1){
    int add = (t >= o && t < BROWS) ? sc[t - o] : 0;
    __syncthreads();
    if (t < BROWS) sc[t] += add;
    __syncthreads();
  }
  if (t < BROWS){
    int off0 = s + sc[t] - rc[t];    // exclusive
    cur[t] = off0;
    int rr = row0 + t;
    if (rr < N_NODES) offs[rr] = off0;
  }
  __syncthreads();
  for (int i = s + t; i < e; i += 256){
    int2 ev = ebkt[i];
    int lr  = ((unsigned)ev.x) >> 17;
    int pos = atomicAdd(&cur[lr], 1);
    edges[pos] = make_int2(ev.x & 0x1FFFF, ev.y);
  }
}

// ---------------------------------------------------------------------------
// Aggregate: one wave per node, quarter-wave per edge. Each lane loads a
// uint2 (4 bf16 channels) -> 512 B per gather covering 4 edges; unroll 4
// -> 16 edges in flight. Coalesced float4 output.
// ---------------------------------------------------------------------------
__global__ __launch_bounds__(256) void agg_kernel(
    const int* __restrict__ offs, const int2* __restrict__ edges,
    const unsigned short* __restrict__ logits, float* __restrict__ out){
  int n    = blockIdx.x * 4 + (threadIdx.x >> 6);
  int lane = threadIdx.x & 63;
  int h    = lane & 15;     // uint2 index within a logits row
  int sel  = lane >> 4;     // which of 4 edges this quarter-wave handles
  int s = offs[n], e = offs[n + 1];
  const uint2* lg = (const uint2*)logits;   // 16 uint2 per node row

  float a0 = 0.f, a1 = 0.f, a2 = 0.f, a3 = 0.f;   // channels 4h..4h+3
  int i = s;
  for (; i + 16 <= e; i += 16){
    int2 e0 = edges[i      + sel];
    int2 e1 = edges[i + 4  + sel];
    int2 e2 = edges[i + 8  + sel];
    int2 e3 = edges[i + 12 + sel];
    uint2 u0 = lg[((size_t)e0.x << 4) + h];
    uint2 u1 = lg[((size_t)e1.x << 4) + h];
    uint2 u2 = lg[((size_t)e2.x << 4) + h];
    uint2 u3 = lg[((size_t)e3.x << 4) + h];
    float v0 = __int_as_float(e0.y), v1 = __int_as_float(e1.y);
    float v2 = __int_as_float(e2.y), v3 = __int_as_float(e3.y);
    a0 = fmaf(v0, bflo(u0.x), a0); a1 = fmaf(v0, bfhi(u0.x), a1);
    a2 = fmaf(v0, bflo(u0.y), a2); a3 = fmaf(v0, bfhi(u0.y), a3);
    a0 = fmaf(v1, bflo(u1.x), a0); a1 = fmaf(v1, bfhi(u1.x), a1);
    a2 = fmaf(v1, bflo(u1.y), a2); a3 = fmaf(v1, bfhi(u1.y), a3);
    a0 = fmaf(v2, bflo(u2.x), a0); a1 = fmaf(v2, bfhi(u2.x), a1);
    a2 = fmaf(v2, bflo(u2.y), a2); a3 = fmaf(v2, bfhi(u2.y), a3);
    a0 = fmaf(v3, bflo(u3.x), a0); a1 = fmaf(v3, bfhi(u3.x), a1);
    a2 = fmaf(v3, bflo(u3.y), a2); a3 = fmaf(v3, bfhi(u3.y), a3);
  }
  for (; i < e; i += 4){
    int idx = i + sel;
    int col = 0; float v = 0.f;
    if (idx < e){ int2 ev = edges[idx]; col = ev.x; v = __int_as_float(ev.y); }
    uint2 u = lg[((size_t)col << 4) + h];
    a0 = fmaf(v, bflo(u.x), a0); a1 = fmaf(v, bfhi(u.x), a1);
    a2 = fmaf(v, bflo(u.y), a2); a3 = fmaf(v, bfhi(u.y), a3);
  }
  a0 += __shfl_xor(a0, 16); a0 += __shfl_xor(a0, 32);
  a1 += __shfl_xor(a1, 16); a1 += __shfl_xor(a1, 32);
  a2 += __shfl_xor(a2, 16); a2 += __shfl_xor(a2, 32);
  a3 += __shfl_xor(a3, 16); a3 += __shfl_xor(a3, 32);
  if (sel == 0){
    float4* op = (float4*)(out + (size_t)n * NCLS);
    op[h] = make_float4(a0, a1, a2, a3);
  }
}

// Fallback if workspace is too small: direct atomic scatter.
__global__ void scatter_atomic(const int* __restrict__ rows, const int* __restrict__ cols,
                               const float* __restrict__ vals,
                               const unsigned short* __restrict__ logits,
                               float* __restrict__ out){
  long g = (long)blockIdx.x * 256 + threadIdx.x;
  int e = (int)(g >> 6), c = (int)(g & 63);
  if (e < N_EDGES){
    float lv = __uint_as_float(((unsigned)logits[(size_t)cols[e] * NCLS + c]) << 16);
    atomicAdd(&out[(size_t)rows[e] * NCLS + c], vals[e] * lv);
  }
}

extern "C" void kernel_launch(void* const* d_in, const int* in_sizes, int n_in,
                              void* d_out, int out_size, void* d_ws, size_t ws_size,
                              hipStream_t stream){
  const float* X     = (const float*)d_in[0];
  const int*   erows = (const int*)  d_in[1];
  const int*   ecols = (const int*)  d_in[2];
  const float* evals = (const float*)d_in[3];
  const float* W1    = (const float*)d_in[4];
  const float* b1    = (const float*)d_in[5];
  const float* W2    = (const float*)d_in[6];
  const float* b2    = (const float*)d_in[7];
  float* out = (float*)d_out;

  char* ws = (char*)d_ws;
  size_t off = 0;
  auto alloc = [&](size_t bytes) -> char* {
    char* p = ws + off;
    off = (off + bytes + 255) & ~(size_t)255;
    return p;
  };
  unsigned short* logits = (unsigned short*)alloc((size_t)N_NODES * NCLS * 2); // 12.8 MB
  unsigned short* w1f    = (unsigned short*)alloc(16*4*64*8 * 2);
  unsigned short* w2f    = (unsigned short*)alloc(2*4*64*8 * 2);
  int* offs  = (int*)alloc((size_t)(N_NODES + 1) * 4);
  int* bcnt  = (int*)alloc((size_t)NBKT * 4);
  int* bbase = (int*)alloc((size_t)(NBKT + 1) * 4);
  int* bcur  = (int*)alloc((size_t)NBKT * 4);
  int2* ebkt  = (int2*)alloc((size_t)N_EDGES * 8);   // bucketed intermediate
  int2* edges = (int2*)alloc((size_t)N_EDGES * 8);   // final CSR (col, val)
  size_t full_need = off;   // ~64.5 MB

  prep_weights<<<144, 256, 0, stream>>>(W1, W2, w1f, w2f);
  mlp_kernel<<<(N_NODES + 63) / 64, 256, 0, stream>>>(X, b1, b2, w1f, w2f, logits);

  if (ws_size >= full_need){
    hipMemsetAsync(bcnt, 0, (size_t)NBKT * 4, stream);
    bucket_count  <<<NCB, 256, 0, stream>>>(erows, bcnt);
    bucket_scan   <<<1, 256, 0, stream>>>(bcnt, bbase, bcur, offs);
    bucket_scatter<<<(N_EDGES + CHUNK - 1) / CHUNK, 256, 0, stream>>>(erows, ecols, evals, bcur, ebkt);
    bucket_sort   <<<NBKT, 256, 0, stream>>>(bbase, ebkt, edges, offs);
    agg_kernel    <<<N_NODES / 4, 256, 0, stream>>>(offs, edges, logits, out);
  } else {
    hipMemsetAsync(out, 0, (size_t)N_NODES * NCLS * 4, stream);
    scatter_atomic<<<(int)(((long)N_EDGES * 64 + 255) / 256), 256, 0, stream>>>(
        erows, ecols, evals, logits, out);
  }
}